// Round 3
// baseline (268.336 us; speedup 1.0000x reference)
//
#include <hip/hip_runtime.h>

// Elementwise 16-step spike recurrence:
//   v=|x|; z=0; o=0;
//   for t: v -= z*h[t]; z = (v > T[t]); o += z*d[t];
//   out = o * sign(x)
// (v-T)/(|v|+1) > 0  <=>  v > T  (denominator strictly positive), so the
// divide is eliminated. z in {0,1} makes z*h and z*d exact products, so fma
// contraction cannot change results vs the reference -> bit-exact (verified
// round 1: absmax 0.0).
//
// Round-3: native ext_vector float4 (nontemporal builtins reject
// HIP_vector_type), unroll x2 independent float4 per iteration (MLP),
// readfirstlane-forced SGPR coefficients, nontemporal loads/stores.

typedef float f32x4 __attribute__((ext_vector_type(4)));

__device__ __forceinline__ float spike_elem(float xj, const float* nh,
                                            const float* dd, const float* TT) {
    float v = fabsf(xj);
    float z = 0.0f;
    float o = 0.0f;
#pragma unroll
    for (int t = 0; t < 16; ++t) {
        v = fmaf(z, nh[t], v);           // v -= z*h[t]   (exact: z in {0,1})
        z = (v > TT[t]) ? 1.0f : 0.0f;   // spike
        o = fmaf(z, dd[t], o);           // o += z*d[t]   (exact product)
    }
    o = copysignf(o, xj);
    return (xj == 0.0f) ? 0.0f : o;      // sign(0) = 0 semantics
}

__global__ __launch_bounds__(256) void spike_scan_kernel(
    const float* __restrict__ x,
    const float* __restrict__ h,
    const float* __restrict__ d,
    const float* __restrict__ T,
    float* __restrict__ out,
    long long n4, long long n)
{
    // Coefficients: force into SGPRs (uniform across the wave).
    float nh[16], dd[16], TT[16];
#pragma unroll
    for (int t = 0; t < 16; ++t) {
        nh[t] = __int_as_float(__builtin_amdgcn_readfirstlane(__float_as_int(-h[t])));
        dd[t] = __int_as_float(__builtin_amdgcn_readfirstlane(__float_as_int(d[t])));
        TT[t] = __int_as_float(__builtin_amdgcn_readfirstlane(__float_as_int(T[t])));
    }

    const f32x4* __restrict__ x4 = reinterpret_cast<const f32x4*>(x);
    f32x4* __restrict__ o4 = reinterpret_cast<f32x4*>(out);

    const long long stride = (long long)gridDim.x * blockDim.x;
    long long i = (long long)blockIdx.x * blockDim.x + threadIdx.x;

    // Main loop: 2 independent float4 in flight per iteration.
    for (; i + stride < n4; i += 2 * stride) {
        f32x4 a = __builtin_nontemporal_load(&x4[i]);
        f32x4 b = __builtin_nontemporal_load(&x4[i + stride]);
        f32x4 ra, rb;
#pragma unroll
        for (int j = 0; j < 4; ++j) ra[j] = spike_elem(a[j], nh, dd, TT);
#pragma unroll
        for (int j = 0; j < 4; ++j) rb[j] = spike_elem(b[j], nh, dd, TT);
        __builtin_nontemporal_store(ra, &o4[i]);
        __builtin_nontemporal_store(rb, &o4[i + stride]);
    }
    // Remainder (at most one float4 per thread).
    for (; i < n4; i += stride) {
        f32x4 a = __builtin_nontemporal_load(&x4[i]);
        f32x4 ra;
#pragma unroll
        for (int j = 0; j < 4; ++j) ra[j] = spike_elem(a[j], nh, dd, TT);
        __builtin_nontemporal_store(ra, &o4[i]);
    }

    // Scalar tail (n not divisible by 4) — block 0 only.
    const long long tail_start = n4 * 4;
    if (blockIdx.x == 0) {
        for (long long k = tail_start + threadIdx.x; k < n; k += blockDim.x) {
            out[k] = spike_elem(x[k], nh, dd, TT);
        }
    }
}

extern "C" void kernel_launch(void* const* d_in, const int* in_sizes, int n_in,
                              void* d_out, int out_size, void* d_ws, size_t ws_size,
                              hipStream_t stream) {
    const float* x = (const float*)d_in[0];
    const float* h = (const float*)d_in[1];
    const float* d = (const float*)d_in[2];
    const float* T = (const float*)d_in[3];
    float* out = (float*)d_out;

    const long long n = (long long)out_size;
    const long long n4 = n / 4;

    const int block = 256;
    int grid = 4096;  // 16 blocks/CU; each thread: 32 float4 -> 16 unrolled iters
    const long long work_items = (n4 + block - 1) / block;
    if (work_items < grid) grid = (int)(work_items > 0 ? work_items : 1);

    spike_scan_kernel<<<grid, block, 0, stream>>>(x, h, d, T, out, n4, n);
}